// Round 14
// baseline (151.029 us; speedup 1.0000x reference)
//
#include <hip/hip_runtime.h>
#include <math.h>

#define BB 10
#define TT 12
#define FF 500
#define HH 200
#define G3 600
#define KP 224      // padded K for h (7*32)
#define NKS 7       // K-steps of 32
#define SLOTS 5     // j-tiles per wave (8 waves * 5 = 40); 4 in regs + 1 in LDS
#define RSLOTS 4
#define GHW 648     // ghf row stride in floats

// ws layout (float units):
#define WS_XW   0        // XW [120][600] fp32
#define WS_XWV  72000    // xw [120]
#define WS_FRAG 72128    // W_hh B-frags: 40 tiles * 7 ks * 64 lanes * 16B = 71680 dwords
#define WS_WHF  143808   // Wh hi/lo B-frags: 14 * 64 * 16B = 3584 dwords

typedef __attribute__((ext_vector_type(8))) short bf16x8;
typedef __attribute__((ext_vector_type(4))) float f32x4;

__device__ __forceinline__ unsigned short f2bf(float f) {
    unsigned int u = __float_as_uint(f);
    u = (u + 0x7fffu + ((u >> 16) & 1u)) >> 16;
    return (unsigned short)u;
}
__device__ __forceinline__ float bf2f(unsigned short h) {
    return __uint_as_float(((unsigned int)h) << 16);
}
__device__ __forceinline__ void cvt_hilo(const float* v, bf16x8& hi, bf16x8& lo) {
    #pragma unroll
    for (int e = 0; e < 8; ++e) {
        unsigned short h = f2bf(v[e]);
        hi[e] = (short)h;
        lo[e] = (short)f2bf(v[e] - bf2f(h));
    }
}

// ---------------- K1: XW via MFMA (hi/lo), xw, W_hh B-frags, Wh hi/lo frags ----------
__global__ __launch_bounds__(256) void prep_kernel(
        const float* __restrict__ x, const float* __restrict__ wx,
        const float* __restrict__ W_ih, const float* __restrict__ W_hh,
        const float* __restrict__ Wh, float* __restrict__ ws) {
    int bl = blockIdx.x, tid = threadIdx.x;
    int wv = tid >> 6, lane = tid & 63;
    int ar = lane & 15, kg = lane >> 4;
    if (bl < 38) {
        int n0 = bl * 16;
        int nj = n0 + ar;
        bool nok = nj < G3;
        const float* wrow = W_ih + (nok ? nj : 0) * FF;
        #pragma unroll
        for (int half = 0; half < 2; ++half) {
            int mt = wv + half * 4;
            int arow = mt * 16 + ar;
            const float* xrow = x + (arow < 120 ? arow : 119) * FF;
            f32x4 a0 = (f32x4){0.f, 0.f, 0.f, 0.f}, a1 = a0, a2 = a0;
            #pragma unroll
            for (int ks = 0; ks < 16; ++ks) {
                int f0 = ks * 32 + kg * 8;
                float xv[8], wv8[8];
                if (f0 + 8 <= FF) {
                    *(float4*)&xv[0]  = *(const float4*)(xrow + f0);
                    *(float4*)&xv[4]  = *(const float4*)(xrow + f0 + 4);
                    *(float4*)&wv8[0] = *(const float4*)(wrow + f0);
                    *(float4*)&wv8[4] = *(const float4*)(wrow + f0 + 4);
                } else {
                    #pragma unroll
                    for (int e = 0; e < 8; ++e) {
                        bool okf = (f0 + e) < FF;
                        xv[e]  = okf ? xrow[f0 + e] : 0.f;
                        wv8[e] = okf ? wrow[f0 + e] : 0.f;
                    }
                }
                bf16x8 xhi, xlo, whi, wlo;
                cvt_hilo(xv, xhi, xlo);
                cvt_hilo(wv8, whi, wlo);
                a0 = __builtin_amdgcn_mfma_f32_16x16x32_bf16(xhi, whi, a0, 0, 0, 0);
                a1 = __builtin_amdgcn_mfma_f32_16x16x32_bf16(xlo, whi, a1, 0, 0, 0);
                a2 = __builtin_amdgcn_mfma_f32_16x16x32_bf16(xhi, wlo, a2, 0, 0, 0);
            }
            #pragma unroll
            for (int r = 0; r < 4; ++r) {
                int bt = mt * 16 + kg * 4 + r;
                if (bt < 120 && nok)
                    ws[WS_XW + bt * G3 + nj] = a0[r] + a1[r] + a2[r];
            }
        }
    } else if (bl < 54) {
        unsigned int* fr = (unsigned int*)(ws + WS_FRAG);
        int base = (bl - 38) * 4480;
        for (int q = tid; q < 4480; q += 256) {
            int d = base + q;
            int v = d & 3, ln = (d >> 2) & 63, pk = d >> 8;
            int ks = pk % NKS, tile = pk / NKS;
            int n = ln & 15;
            int k = ks * 32 + (ln >> 4) * 8 + 2 * v;
            unsigned int w = 0;
            if (k < HH && n < 15) {
                int j = 40 * n + tile;   // < 600
                w = (unsigned int)f2bf(W_hh[j * HH + k]) |
                    ((unsigned int)f2bf(W_hh[j * HH + k + 1]) << 16);
            }
            fr[d] = w;
        }
    } else if (bl < 62) {
        int dte = (bl - 54) * 15 + (tid >> 4), l = tid & 15;
        if (tid < 240) {
            float p = 0.f;
            for (int f = l; f < FF; f += 16) p += x[dte * FF + f] * wx[f];
            p += __shfl_xor(p, 8);
            p += __shfl_xor(p, 4);
            p += __shfl_xor(p, 2);
            p += __shfl_xor(p, 1);
            if (l == 0) ws[WS_XWV + dte] = p;
        }
    } else {
        unsigned int* fr = (unsigned int*)(ws + WS_WHF);
        for (int d = tid; d < 3584; d += 256) {
            int v = d & 3, ln = (d >> 2) & 63, pk = d >> 8;
            int qq = pk & 1, ks = pk >> 1;
            int t = ln & 15, k = ks * 32 + (ln >> 4) * 8 + 2 * v;
            unsigned int w = 0;
            if (t < TT && k < HH) {
                float f0 = Wh[t * HH + k], f1 = Wh[t * HH + k + 1];
                if (qq == 0) {
                    w = (unsigned int)f2bf(f0) | ((unsigned int)f2bf(f1) << 16);
                } else {
                    float l0 = f0 - bf2f(f2bf(f0)), l1 = f1 - bf2f(f2bf(f1));
                    w = (unsigned int)f2bf(l0) | ((unsigned int)f2bf(l1) << 16);
                }
            }
            fr[d] = w;
        }
    }
}

// hbf: bf16 h [16 rows(b)][KP], XOR-swizzled (ushort idx ^ (b&7)<<3)
__device__ __forceinline__ int hbf_idx(int r, int k) {
    return (r * KP + k) ^ ((r & 7) << 3);
}

// ---------------- K2: single-block 12-step recurrence, 8 waves ----------------
// R13 base + B1 chunked: fixed 12-trip in 4 chunks of 3 t's; chunk-0 loads hoisted
// before softmax (static addresses). 36 live regs/chunk, single-buffered (R10's
// 72-reg double-buffer spilled; this must stay under the unified 256 budget).
__global__ __attribute__((amdgpu_waves_per_eu(2, 2))) __launch_bounds__(512)
void recurrence_kernel(
        const float* __restrict__ guidance, const float* __restrict__ bh,
        const float* __restrict__ b_ih, const float* __restrict__ b_hh,
        const float* __restrict__ h0, const float* __restrict__ ws,
        float* __restrict__ out) {
    const float* XW  = ws + WS_XW;
    const float* xww = ws + WS_XWV;

    __shared__ __align__(16) float ghf[16 * GHW];           // 41.5 KB
    __shared__ __align__(16) unsigned short hbf[16 * KP];   // 7 KB
    __shared__ __align__(16) bf16x8 wlds[8][NKS][64];       // 57 KB (1 tile/wave)
    __shared__ __align__(16) bf16x8 wh_lds[2][NKS][64];     // 14 KB
    __shared__ __align__(16) float bsum_s[2 * HH];
    __shared__ __align__(16) float bihn_s[HH];
    __shared__ __align__(16) float bhhn_s[HH];
    __shared__ float guid_s[BB][TT], zr_s[BB][TT], xw_s[BB][TT];
    __shared__ float a_w[8][TT][12];
    __shared__ float bh_s[TT];

    int tid = threadIdx.x, wv = tid >> 6, lane = tid & 63;
    int ar = lane & 15, kg = lane >> 4;

    bf16x8 bfr[RSLOTS][NKS];
    {
        const bf16x8* fragp = (const bf16x8*)(ws + WS_FRAG);
        #pragma unroll
        for (int s = 0; s < RSLOTS; ++s)
            #pragma unroll
            for (int ks = 0; ks < NKS; ++ks)
                bfr[s][ks] = fragp[((SLOTS * wv + s) * NKS + ks) * 64 + lane];
        #pragma unroll
        for (int ks = 0; ks < NKS; ++ks)
            wlds[wv][ks][lane] = fragp[((SLOTS * wv + RSLOTS) * NKS + ks) * 64 + lane];
        const bf16x8* whp = (const bf16x8*)(ws + WS_WHF);
        for (int u = tid; u < 2 * NKS * 64; u += 512) {
            int l = u & 63, pk = u >> 6;
            wh_lds[pk & 1][pk >> 1][l] = whp[u];
        }
    }
    if (tid < BB * TT) {
        guid_s[tid / TT][tid % TT] = guidance[tid];
        xw_s[tid / TT][tid % TT]   = xww[tid];
    }
    for (int idx = tid; idx < 2 * HH; idx += 512) bsum_s[idx] = b_ih[idx] + b_hh[idx];
    for (int idx = tid; idx < HH; idx += 512) {
        bihn_s[idx] = b_ih[idx + 2 * HH];
        bhhn_s[idx] = b_hh[idx + 2 * HH];
    }
    if (tid < TT) bh_s[tid] = bh[tid];
    for (int idx = tid; idx < 16 * KP / 2; idx += 512) ((unsigned int*)hbf)[idx] = 0;
    float4 hq = (float4){0.f, 0.f, 0.f, 0.f};
    if (tid < 500) hq = *(const float4*)(h0 + (tid / 50) * HH + (tid % 50) * 4);
    __syncthreads();
    if (tid < 500) {
        int b = tid / 50, k = (tid % 50) * 4;
        unsigned int u01 = (unsigned int)f2bf(hq.x) | ((unsigned int)f2bf(hq.y) << 16);
        unsigned int u23 = (unsigned int)f2bf(hq.z) | ((unsigned int)f2bf(hq.w) << 16);
        *(uint2*)&hbf[hbf_idx(b, k)] = (uint2){u01, u23};
    }
    if (tid < BB) {
        float run = 0.f;
        for (int i = 0; i < TT; ++i) {
            zr_s[tid][i] = (run == 0.f) ? 1.f : 0.f;
            run += guid_s[tid][i];
        }
    }
    __syncthreads();

    bool vB = tid < 500;
    int bB = vB ? tid / 50 : 0;
    int cB = vB ? tid % 50 : 0;
    const float* xwbase = XW + bB * (TT * G3) + cB * 4;

    #pragma unroll 1
    for (int i = 0; i < TT; ++i) {
        // ---- A-frags ----
        bf16x8 ahi[NKS];
        #pragma unroll
        for (int ks = 0; ks < NKS; ++ks)
            ahi[ks] = *(const bf16x8*)&hbf[hbf_idx(ar, ks * 32 + kg * 8)];
        // ---- sc MFMA (2 parallel chains, hi/lo Wh) ----
        f32x4 sch = (f32x4){0.f, 0.f, 0.f, 0.f};
        f32x4 scl = (f32x4){0.f, 0.f, 0.f, 0.f};
        #pragma unroll
        for (int ks = 0; ks < NKS; ++ks) {
            sch = __builtin_amdgcn_mfma_f32_16x16x32_bf16(ahi[ks], wh_lds[0][ks][lane], sch, 0, 0, 0);
            scl = __builtin_amdgcn_mfma_f32_16x16x32_bf16(ahi[ks], wh_lds[1][ks][lane], scl, 0, 0, 0);
        }
        // ---- B2 MFMAs ----
        {
            f32x4 acc[SLOTS];
            #pragma unroll
            for (int s = 0; s < RSLOTS; ++s) {
                acc[s] = (f32x4){0.f, 0.f, 0.f, 0.f};
                #pragma unroll
                for (int ks = 0; ks < NKS; ++ks)
                    acc[s] = __builtin_amdgcn_mfma_f32_16x16x32_bf16(ahi[ks], bfr[s][ks], acc[s], 0, 0, 0);
            }
            acc[RSLOTS] = (f32x4){0.f, 0.f, 0.f, 0.f};
            #pragma unroll
            for (int ks = 0; ks < NKS; ++ks) {
                bf16x8 bw = wlds[wv][ks][lane];
                acc[RSLOTS] = __builtin_amdgcn_mfma_f32_16x16x32_bf16(ahi[ks], bw, acc[RSLOTS], 0, 0, 0);
            }
            int xr = (kg & 3) << 2;
            int base0 = 40 * ar + 5 * wv;
            #pragma unroll
            for (int r = 0; r < 4; ++r) {
                int b = 4 * kg + r;
                if (b < BB) {
                    int base = b * GHW + base0;
                    #pragma unroll
                    for (int s = 0; s < SLOTS; ++s)
                        ghf[(base + s) ^ xr] = acc[s][r];
                }
            }
        }
        // ---- B1 chunk-0 loads (static addresses; hide under softmax) ----
        float4 vr0[3], vz0[3], vn0[3];
        if (vB) {
            #pragma unroll
            for (int u = 0; u < 3; ++u) {
                vr0[u] = *(const float4*)(xwbase + u * G3);
                vz0[u] = *(const float4*)(xwbase + u * G3 + HH);
                vn0[u] = *(const float4*)(xwbase + u * G3 + 2 * HH);
            }
        }
        // ---- softmax over b (per t = ar), wave-local result ----
        {
            int t = ar;
            float vv[4], mx = -3e38f;
            #pragma unroll
            for (int r = 0; r < 4; ++r) {
                int b = 4 * kg + r;
                float val = -3e38f;
                if (b < BB && t < TT) {
                    float ge = (t == i) ? 1.f : (zr_s[b][i] != 0.f ? 1.f : guid_s[b][t]);
                    val = ge * xw_s[b][t] + sch[r] + scl[r] + bh_s[t];
                }
                vv[r] = val;
                mx = fmaxf(mx, val);
            }
            mx = fmaxf(mx, __shfl_xor(mx, 16));
            mx = fmaxf(mx, __shfl_xor(mx, 32));
            float ee[4], sum = 0.f;
            #pragma unroll
            for (int r = 0; r < 4; ++r) {
                ee[r] = (vv[r] > -1e37f) ? __expf(vv[r] - mx) : 0.f;
                sum += ee[r];
            }
            sum += __shfl_xor(sum, 16);
            sum += __shfl_xor(sum, 32);
            float inv = 1.f / sum;
            #pragma unroll
            for (int r = 0; r < 4; ++r) {
                int b = 4 * kg + r;
                if (b < BB && t < TT) a_w[wv][t][b] = (t <= i) ? ee[r] * inv : 0.f;
            }
        }
        // ---- B1: fixed 12 trips, 4 chunks of 3 (a_w[t>i]==0 -> exact) ----
        float4 gi_r = (float4){0.f, 0.f, 0.f, 0.f};
        float4 gi_z = gi_r, gi_n = gi_r;
        if (vB) {
            float a12[TT];
            #pragma unroll
            for (int t = 0; t < TT; ++t) a12[t] = a_w[wv][t][bB];
            // chunk 0 (preloaded)
            #pragma unroll
            for (int u = 0; u < 3; ++u) {
                float aa = a12[u];
                gi_r.x += aa * vr0[u].x; gi_r.y += aa * vr0[u].y;
                gi_r.z += aa * vr0[u].z; gi_r.w += aa * vr0[u].w;
                gi_z.x += aa * vz0[u].x; gi_z.y += aa * vz0[u].y;
                gi_z.z += aa * vz0[u].z; gi_z.w += aa * vz0[u].w;
                gi_n.x += aa * vn0[u].x; gi_n.y += aa * vn0[u].y;
                gi_n.z += aa * vn0[u].z; gi_n.w += aa * vn0[u].w;
            }
            // chunks 1..3: load 9 float4 together, then FMA (single-buffered)
            #pragma unroll
            for (int c = 1; c < 4; ++c) {
                float4 vr[3], vz[3], vn[3];
                #pragma unroll
                for (int u = 0; u < 3; ++u) {
                    int t = c * 3 + u;
                    vr[u] = *(const float4*)(xwbase + t * G3);
                    vz[u] = *(const float4*)(xwbase + t * G3 + HH);
                    vn[u] = *(const float4*)(xwbase + t * G3 + 2 * HH);
                }
                #pragma unroll
                for (int u = 0; u < 3; ++u) {
                    float aa = a12[c * 3 + u];
                    gi_r.x += aa * vr[u].x; gi_r.y += aa * vr[u].y;
                    gi_r.z += aa * vr[u].z; gi_r.w += aa * vr[u].w;
                    gi_z.x += aa * vz[u].x; gi_z.y += aa * vz[u].y;
                    gi_z.z += aa * vz[u].z; gi_z.w += aa * vz[u].w;
                    gi_n.x += aa * vn[u].x; gi_n.y += aa * vn[u].y;
                    gi_n.z += aa * vn[u].z; gi_n.w += aa * vn[u].w;
                }
            }
        }
        __syncthreads();   // bar1: ghf ready

        // ---- P3: GRU update; gi in regs, gh from ghf; hbf refresh ----
        if (vB) {
            int b = bB, k = cB * 4;
            int xr = ((b >> 2) & 3) << 2;
            float4 ghr = *(const float4*)&ghf[(b * GHW + k) ^ xr];
            float4 ghz = *(const float4*)&ghf[(b * GHW + k + HH) ^ xr];
            float4 ghn = *(const float4*)&ghf[(b * GHW + k + 2 * HH) ^ xr];
            float4 br4 = *(const float4*)&bsum_s[k];
            float4 bz4 = *(const float4*)&bsum_s[k + HH];
            float4 bni = *(const float4*)&bihn_s[k];
            float4 bnh = *(const float4*)&bhhn_s[k];
            float4 hn;
            float* pgir = (float*)&gi_r; float* pgiz = (float*)&gi_z; float* pgin = (float*)&gi_n;
            float* pghr = (float*)&ghr;  float* pghz = (float*)&ghz;  float* pghn = (float*)&ghn;
            float* pbr = (float*)&br4;   float* pbz = (float*)&bz4;
            float* pbi = (float*)&bni;   float* pbh = (float*)&bnh;
            float* ph  = (float*)&hq;    float* phn = (float*)&hn;
            #pragma unroll
            for (int e = 0; e < 4; ++e) {
                float r = 1.f / (1.f + __expf(-(pgir[e] + pghr[e] + pbr[e])));
                float z = 1.f / (1.f + __expf(-(pgiz[e] + pghz[e] + pbz[e])));
                float xx = pgin[e] + pbi[e] + r * (pghn[e] + pbh[e]);
                float e2 = __expf(2.f * xx);
                float n = 1.f - 2.f / (e2 + 1.f);
                phn[e] = (1.f - z) * n + z * ph[e];
            }
            hq = hn;
            unsigned int u01 = (unsigned int)f2bf(hn.x) | ((unsigned int)f2bf(hn.y) << 16);
            unsigned int u23 = (unsigned int)f2bf(hn.z) | ((unsigned int)f2bf(hn.w) << 16);
            *(uint2*)&hbf[hbf_idx(b, k)] = (uint2){u01, u23};
        }
        __syncthreads();   // bar2: hbf ready for next step
    }

    if (vB) *(float4*)(out + bB * HH + cB * 4) = hq;
}

extern "C" void kernel_launch(void* const* d_in, const int* in_sizes, int n_in,
                              void* d_out, int out_size, void* d_ws, size_t ws_size,
                              hipStream_t stream) {
    (void)in_sizes; (void)n_in; (void)out_size; (void)ws_size;
    const float* x    = (const float*)d_in[0];
    const float* guid = (const float*)d_in[1];
    const float* wx   = (const float*)d_in[2];
    const float* Wh   = (const float*)d_in[3];
    const float* bh   = (const float*)d_in[4];
    const float* W_ih = (const float*)d_in[5];
    const float* W_hh = (const float*)d_in[6];
    const float* b_ih = (const float*)d_in[7];
    const float* b_hh = (const float*)d_in[8];
    const float* h0   = (const float*)d_in[9];
    float* ws  = (float*)d_ws;
    float* out = (float*)d_out;

    hipLaunchKernelGGL(prep_kernel, dim3(63), dim3(256), 0, stream,
                       x, wx, W_ih, W_hh, Wh, ws);
    hipLaunchKernelGGL(recurrence_kernel, dim3(1), dim3(512), 0, stream,
                       guid, bh, b_ih, b_hh, h0, ws, out);
}

// Round 15
// 76.155 us; speedup vs baseline: 1.9832x; 1.9832x over previous
//
#include <hip/hip_runtime.h>
#include <math.h>

#define BB 10
#define TT 12
#define FF 500
#define HH 200
#define G3 600
#define KP 224      // padded K for h (7*32)
#define NKS 7       // K-steps of 32
#define SLOTS 5     // j-tiles per wave (8 waves * 5 = 40); 4 in regs + 1 in LDS
#define RSLOTS 4
#define GHW 648     // ghf row stride in floats

// ws layout (float units):
#define WS_XW   0        // XW [120][600] fp32
#define WS_XWV  72000    // xw [120]
#define WS_FRAG 72128    // W_hh B-frags: 40 tiles * 7 ks * 64 lanes * 16B = 71680 dwords
#define WS_WHF  143808   // Wh hi/lo B-frags: 14 * 64 * 16B = 3584 dwords

typedef __attribute__((ext_vector_type(8))) short bf16x8;
typedef __attribute__((ext_vector_type(4))) float f32x4;

__device__ __forceinline__ unsigned short f2bf(float f) {
    unsigned int u = __float_as_uint(f);
    u = (u + 0x7fffu + ((u >> 16) & 1u)) >> 16;
    return (unsigned short)u;
}
__device__ __forceinline__ float bf2f(unsigned short h) {
    return __uint_as_float(((unsigned int)h) << 16);
}
__device__ __forceinline__ void cvt_hilo(const float* v, bf16x8& hi, bf16x8& lo) {
    #pragma unroll
    for (int e = 0; e < 8; ++e) {
        unsigned short h = f2bf(v[e]);
        hi[e] = (short)h;
        lo[e] = (short)f2bf(v[e] - bf2f(h));
    }
}

// ---------------- K1: XW via MFMA (hi/lo), xw, W_hh B-frags, Wh hi/lo frags ----------
// 76 blocks for the XW-GEMM: one (m-tile, n-strip) pair per block (R13 did 2 serial
// m-tiles per block; this halves the prep critical path; K2 untouched).
__global__ __launch_bounds__(256) void prep_kernel(
        const float* __restrict__ x, const float* __restrict__ wx,
        const float* __restrict__ W_ih, const float* __restrict__ W_hh,
        const float* __restrict__ Wh, float* __restrict__ ws) {
    int bl = blockIdx.x, tid = threadIdx.x;
    int wv = tid >> 6, lane = tid & 63;
    int ar = lane & 15, kg = lane >> 4;
    if (bl < 76) {
        // strip = bl/2 (n0 = strip*16); half = bl&1; m-tile = wv + half*4
        int n0 = (bl >> 1) * 16;
        int nj = n0 + ar;
        bool nok = nj < G3;
        const float* wrow = W_ih + (nok ? nj : 0) * FF;
        int mt = wv + (bl & 1) * 4;
        int arow = mt * 16 + ar;
        const float* xrow = x + (arow < 120 ? arow : 119) * FF;
        f32x4 a0 = (f32x4){0.f, 0.f, 0.f, 0.f}, a1 = a0, a2 = a0;
        #pragma unroll
        for (int ks = 0; ks < 16; ++ks) {
            int f0 = ks * 32 + kg * 8;
            float xv[8], wv8[8];
            if (f0 + 8 <= FF) {
                *(float4*)&xv[0]  = *(const float4*)(xrow + f0);
                *(float4*)&xv[4]  = *(const float4*)(xrow + f0 + 4);
                *(float4*)&wv8[0] = *(const float4*)(wrow + f0);
                *(float4*)&wv8[4] = *(const float4*)(wrow + f0 + 4);
            } else {
                #pragma unroll
                for (int e = 0; e < 8; ++e) {
                    bool okf = (f0 + e) < FF;
                    xv[e]  = okf ? xrow[f0 + e] : 0.f;
                    wv8[e] = okf ? wrow[f0 + e] : 0.f;
                }
            }
            bf16x8 xhi, xlo, whi, wlo;
            cvt_hilo(xv, xhi, xlo);
            cvt_hilo(wv8, whi, wlo);
            a0 = __builtin_amdgcn_mfma_f32_16x16x32_bf16(xhi, whi, a0, 0, 0, 0);
            a1 = __builtin_amdgcn_mfma_f32_16x16x32_bf16(xlo, whi, a1, 0, 0, 0);
            a2 = __builtin_amdgcn_mfma_f32_16x16x32_bf16(xhi, wlo, a2, 0, 0, 0);
        }
        #pragma unroll
        for (int r = 0; r < 4; ++r) {
            int bt = mt * 16 + kg * 4 + r;
            if (bt < 120 && nok)
                ws[WS_XW + bt * G3 + nj] = a0[r] + a1[r] + a2[r];
        }
    } else if (bl < 92) {
        unsigned int* fr = (unsigned int*)(ws + WS_FRAG);
        int base = (bl - 76) * 4480;
        for (int q = tid; q < 4480; q += 256) {
            int d = base + q;
            int v = d & 3, ln = (d >> 2) & 63, pk = d >> 8;
            int ks = pk % NKS, tile = pk / NKS;
            int n = ln & 15;
            int k = ks * 32 + (ln >> 4) * 8 + 2 * v;
            unsigned int w = 0;
            if (k < HH && n < 15) {
                int j = 40 * n + tile;   // < 600
                w = (unsigned int)f2bf(W_hh[j * HH + k]) |
                    ((unsigned int)f2bf(W_hh[j * HH + k + 1]) << 16);
            }
            fr[d] = w;
        }
    } else if (bl < 100) {
        int dte = (bl - 92) * 15 + (tid >> 4), l = tid & 15;
        if (tid < 240) {
            float p = 0.f;
            for (int f = l; f < FF; f += 16) p += x[dte * FF + f] * wx[f];
            p += __shfl_xor(p, 8);
            p += __shfl_xor(p, 4);
            p += __shfl_xor(p, 2);
            p += __shfl_xor(p, 1);
            if (l == 0) ws[WS_XWV + dte] = p;
        }
    } else {
        unsigned int* fr = (unsigned int*)(ws + WS_WHF);
        for (int d = tid; d < 3584; d += 256) {
            int v = d & 3, ln = (d >> 2) & 63, pk = d >> 8;
            int qq = pk & 1, ks = pk >> 1;
            int t = ln & 15, k = ks * 32 + (ln >> 4) * 8 + 2 * v;
            unsigned int w = 0;
            if (t < TT && k < HH) {
                float f0 = Wh[t * HH + k], f1 = Wh[t * HH + k + 1];
                if (qq == 0) {
                    w = (unsigned int)f2bf(f0) | ((unsigned int)f2bf(f1) << 16);
                } else {
                    float l0 = f0 - bf2f(f2bf(f0)), l1 = f1 - bf2f(f2bf(f1));
                    w = (unsigned int)f2bf(l0) | ((unsigned int)f2bf(l1) << 16);
                }
            }
            fr[d] = w;
        }
    }
}

// hbf: bf16 h [16 rows(b)][KP], XOR-swizzled (ushort idx ^ (b&7)<<3)
__device__ __forceinline__ int hbf_idx(int r, int k) {
    return (r * KP + k) ^ ((r & 7) << 3);
}

// ---------------- K2: single-block 12-step recurrence, 8 waves (R9/R13-verbatim) ----
// DO NOT add live registers to the K-loop: at 2 waves/SIMD the unified budget is
// 256/wave and this kernel sits ~15 regs under it. R10 and R14 both proved that
// B1 pipelining via extra in-flight registers spills (VGPR pins at 128, 2x slower).
__global__ __attribute__((amdgpu_waves_per_eu(2, 2))) __launch_bounds__(512)
void recurrence_kernel(
        const float* __restrict__ guidance, const float* __restrict__ bh,
        const float* __restrict__ b_ih, const float* __restrict__ b_hh,
        const float* __restrict__ h0, const float* __restrict__ ws,
        float* __restrict__ out) {
    const float* XW  = ws + WS_XW;
    const float* xww = ws + WS_XWV;

    __shared__ __align__(16) float ghf[16 * GHW];           // 41.5 KB
    __shared__ __align__(16) unsigned short hbf[16 * KP];   // 7 KB
    __shared__ __align__(16) bf16x8 wlds[8][NKS][64];       // 57 KB (1 tile/wave)
    __shared__ __align__(16) bf16x8 wh_lds[2][NKS][64];     // 14 KB
    __shared__ __align__(16) float bsum_s[2 * HH];
    __shared__ __align__(16) float bihn_s[HH];
    __shared__ __align__(16) float bhhn_s[HH];
    __shared__ float guid_s[BB][TT], zr_s[BB][TT], xw_s[BB][TT];
    __shared__ float a_w[8][TT][12];
    __shared__ float bh_s[TT];

    int tid = threadIdx.x, wv = tid >> 6, lane = tid & 63;
    int ar = lane & 15, kg = lane >> 4;

    bf16x8 bfr[RSLOTS][NKS];
    {
        const bf16x8* fragp = (const bf16x8*)(ws + WS_FRAG);
        #pragma unroll
        for (int s = 0; s < RSLOTS; ++s)
            #pragma unroll
            for (int ks = 0; ks < NKS; ++ks)
                bfr[s][ks] = fragp[((SLOTS * wv + s) * NKS + ks) * 64 + lane];
        #pragma unroll
        for (int ks = 0; ks < NKS; ++ks)
            wlds[wv][ks][lane] = fragp[((SLOTS * wv + RSLOTS) * NKS + ks) * 64 + lane];
        const bf16x8* whp = (const bf16x8*)(ws + WS_WHF);
        for (int u = tid; u < 2 * NKS * 64; u += 512) {
            int l = u & 63, pk = u >> 6;
            wh_lds[pk & 1][pk >> 1][l] = whp[u];
        }
    }
    if (tid < BB * TT) {
        guid_s[tid / TT][tid % TT] = guidance[tid];
        xw_s[tid / TT][tid % TT]   = xww[tid];
    }
    for (int idx = tid; idx < 2 * HH; idx += 512) bsum_s[idx] = b_ih[idx] + b_hh[idx];
    for (int idx = tid; idx < HH; idx += 512) {
        bihn_s[idx] = b_ih[idx + 2 * HH];
        bhhn_s[idx] = b_hh[idx + 2 * HH];
    }
    if (tid < TT) bh_s[tid] = bh[tid];
    for (int idx = tid; idx < 16 * KP / 2; idx += 512) ((unsigned int*)hbf)[idx] = 0;
    float4 hq = (float4){0.f, 0.f, 0.f, 0.f};
    if (tid < 500) hq = *(const float4*)(h0 + (tid / 50) * HH + (tid % 50) * 4);
    __syncthreads();
    if (tid < 500) {
        int b = tid / 50, k = (tid % 50) * 4;
        unsigned int u01 = (unsigned int)f2bf(hq.x) | ((unsigned int)f2bf(hq.y) << 16);
        unsigned int u23 = (unsigned int)f2bf(hq.z) | ((unsigned int)f2bf(hq.w) << 16);
        *(uint2*)&hbf[hbf_idx(b, k)] = (uint2){u01, u23};
    }
    if (tid < BB) {
        float run = 0.f;
        for (int i = 0; i < TT; ++i) {
            zr_s[tid][i] = (run == 0.f) ? 1.f : 0.f;
            run += guid_s[tid][i];
        }
    }
    __syncthreads();

    bool vB = tid < 500;
    int bB = vB ? tid / 50 : 0;
    int cB = vB ? tid % 50 : 0;
    const float* xwbase = XW + bB * (TT * G3) + cB * 4;

    #pragma unroll 1
    for (int i = 0; i < TT; ++i) {
        // ---- A-frags ----
        bf16x8 ahi[NKS];
        #pragma unroll
        for (int ks = 0; ks < NKS; ++ks)
            ahi[ks] = *(const bf16x8*)&hbf[hbf_idx(ar, ks * 32 + kg * 8)];
        // ---- sc MFMA (2 parallel chains, hi/lo Wh) ----
        f32x4 sch = (f32x4){0.f, 0.f, 0.f, 0.f};
        f32x4 scl = (f32x4){0.f, 0.f, 0.f, 0.f};
        #pragma unroll
        for (int ks = 0; ks < NKS; ++ks) {
            sch = __builtin_amdgcn_mfma_f32_16x16x32_bf16(ahi[ks], wh_lds[0][ks][lane], sch, 0, 0, 0);
            scl = __builtin_amdgcn_mfma_f32_16x16x32_bf16(ahi[ks], wh_lds[1][ks][lane], scl, 0, 0, 0);
        }
        // ---- B2 MFMAs (independent; hide sc chain latency) ----
        {
            f32x4 acc[SLOTS];
            #pragma unroll
            for (int s = 0; s < RSLOTS; ++s) {
                acc[s] = (f32x4){0.f, 0.f, 0.f, 0.f};
                #pragma unroll
                for (int ks = 0; ks < NKS; ++ks)
                    acc[s] = __builtin_amdgcn_mfma_f32_16x16x32_bf16(ahi[ks], bfr[s][ks], acc[s], 0, 0, 0);
            }
            acc[RSLOTS] = (f32x4){0.f, 0.f, 0.f, 0.f};
            #pragma unroll
            for (int ks = 0; ks < NKS; ++ks) {
                bf16x8 bw = wlds[wv][ks][lane];
                acc[RSLOTS] = __builtin_amdgcn_mfma_f32_16x16x32_bf16(ahi[ks], bw, acc[RSLOTS], 0, 0, 0);
            }
            int xr = (kg & 3) << 2;
            int base0 = 40 * ar + 5 * wv;
            #pragma unroll
            for (int r = 0; r < 4; ++r) {
                int b = 4 * kg + r;
                if (b < BB) {
                    int base = b * GHW + base0;
                    #pragma unroll
                    for (int s = 0; s < SLOTS; ++s)
                        ghf[(base + s) ^ xr] = acc[s][r];
                }
            }
        }
        // ---- softmax over b (per t = ar), wave-local result ----
        {
            int t = ar;
            float vv[4], mx = -3e38f;
            #pragma unroll
            for (int r = 0; r < 4; ++r) {
                int b = 4 * kg + r;
                float val = -3e38f;
                if (b < BB && t < TT) {
                    float ge = (t == i) ? 1.f : (zr_s[b][i] != 0.f ? 1.f : guid_s[b][t]);
                    val = ge * xw_s[b][t] + sch[r] + scl[r] + bh_s[t];
                }
                vv[r] = val;
                mx = fmaxf(mx, val);
            }
            mx = fmaxf(mx, __shfl_xor(mx, 16));
            mx = fmaxf(mx, __shfl_xor(mx, 32));
            float ee[4], sum = 0.f;
            #pragma unroll
            for (int r = 0; r < 4; ++r) {
                ee[r] = (vv[r] > -1e37f) ? __expf(vv[r] - mx) : 0.f;
                sum += ee[r];
            }
            sum += __shfl_xor(sum, 16);
            sum += __shfl_xor(sum, 32);
            float inv = 1.f / sum;
            #pragma unroll
            for (int r = 0; r < 4; ++r) {
                int b = 4 * kg + r;
                if (b < BB && t < TT) a_w[wv][t][b] = (t <= i) ? ee[r] * inv : 0.f;
            }
        }
        // ---- B1: gi gates in REGISTERS; thread == P3 thread (R9 form) ----
        float4 gi_r = (float4){0.f, 0.f, 0.f, 0.f};
        float4 gi_z = gi_r, gi_n = gi_r;
        if (vB) {
            float a12[TT];
            #pragma unroll
            for (int t = 0; t < TT; ++t) a12[t] = a_w[wv][t][bB];
            for (int t = 0; t <= i; ++t) {
                float aa = a12[t];
                float4 vr = *(const float4*)(xwbase + t * G3);
                float4 vz = *(const float4*)(xwbase + t * G3 + HH);
                float4 vn = *(const float4*)(xwbase + t * G3 + 2 * HH);
                gi_r.x += aa * vr.x; gi_r.y += aa * vr.y; gi_r.z += aa * vr.z; gi_r.w += aa * vr.w;
                gi_z.x += aa * vz.x; gi_z.y += aa * vz.y; gi_z.z += aa * vz.z; gi_z.w += aa * vz.w;
                gi_n.x += aa * vn.x; gi_n.y += aa * vn.y; gi_n.z += aa * vn.z; gi_n.w += aa * vn.w;
            }
        }
        __syncthreads();   // bar1: ghf ready

        // ---- P3: GRU update; gi in regs, gh from ghf; hbf refresh ----
        if (vB) {
            int b = bB, k = cB * 4;
            int xr = ((b >> 2) & 3) << 2;
            float4 ghr = *(const float4*)&ghf[(b * GHW + k) ^ xr];
            float4 ghz = *(const float4*)&ghf[(b * GHW + k + HH) ^ xr];
            float4 ghn = *(const float4*)&ghf[(b * GHW + k + 2 * HH) ^ xr];
            float4 br4 = *(const float4*)&bsum_s[k];
            float4 bz4 = *(const float4*)&bsum_s[k + HH];
            float4 bni = *(const float4*)&bihn_s[k];
            float4 bnh = *(const float4*)&bhhn_s[k];
            float4 hn;
            float* pgir = (float*)&gi_r; float* pgiz = (float*)&gi_z; float* pgin = (float*)&gi_n;
            float* pghr = (float*)&ghr;  float* pghz = (float*)&ghz;  float* pghn = (float*)&ghn;
            float* pbr = (float*)&br4;   float* pbz = (float*)&bz4;
            float* pbi = (float*)&bni;   float* pbh = (float*)&bnh;
            float* ph  = (float*)&hq;    float* phn = (float*)&hn;
            #pragma unroll
            for (int e = 0; e < 4; ++e) {
                float r = 1.f / (1.f + __expf(-(pgir[e] + pghr[e] + pbr[e])));
                float z = 1.f / (1.f + __expf(-(pgiz[e] + pghz[e] + pbz[e])));
                float xx = pgin[e] + pbi[e] + r * (pghn[e] + pbh[e]);
                float e2 = __expf(2.f * xx);
                float n = 1.f - 2.f / (e2 + 1.f);
                phn[e] = (1.f - z) * n + z * ph[e];
            }
            hq = hn;
            unsigned int u01 = (unsigned int)f2bf(hn.x) | ((unsigned int)f2bf(hn.y) << 16);
            unsigned int u23 = (unsigned int)f2bf(hn.z) | ((unsigned int)f2bf(hn.w) << 16);
            *(uint2*)&hbf[hbf_idx(b, k)] = (uint2){u01, u23};
        }
        __syncthreads();   // bar2: hbf ready for next step
    }

    if (vB) *(float4*)(out + bB * HH + cB * 4) = hq;
}

extern "C" void kernel_launch(void* const* d_in, const int* in_sizes, int n_in,
                              void* d_out, int out_size, void* d_ws, size_t ws_size,
                              hipStream_t stream) {
    (void)in_sizes; (void)n_in; (void)out_size; (void)ws_size;
    const float* x    = (const float*)d_in[0];
    const float* guid = (const float*)d_in[1];
    const float* wx   = (const float*)d_in[2];
    const float* Wh   = (const float*)d_in[3];
    const float* bh   = (const float*)d_in[4];
    const float* W_ih = (const float*)d_in[5];
    const float* W_hh = (const float*)d_in[6];
    const float* b_ih = (const float*)d_in[7];
    const float* b_hh = (const float*)d_in[8];
    const float* h0   = (const float*)d_in[9];
    float* ws  = (float*)d_ws;
    float* out = (float*)d_out;

    hipLaunchKernelGGL(prep_kernel, dim3(101), dim3(256), 0, stream,
                       x, wx, W_ih, W_hh, Wh, ws);
    hipLaunchKernelGGL(recurrence_kernel, dim3(1), dim3(512), 0, stream,
                       guid, bh, b_ih, b_hh, h0, ws, out);
}